// Round 4
// baseline (190.888 us; speedup 1.0000x reference)
//
#include <hip/hip_runtime.h>
#include <stdint.h>

#define DI __device__ __forceinline__

typedef float f32x4 __attribute__((ext_vector_type(4)));
typedef short bf16x8 __attribute__((ext_vector_type(8)));

DI uint16_t f2bf(float f) {
    union { float f; uint32_t u; } v; v.f = f;
    uint32_t r = v.u + 0x7FFF + ((v.u >> 16) & 1);
    return (uint16_t)(r >> 16);
}
DI float bf2f(uint16_t h) {
    union { uint32_t u; float f; } v; v.u = ((uint32_t)h) << 16;
    return v.f;
}
DI bf16x8 cvt8(float4 lo, float4 hi) {
    union { uint4 u; bf16x8 v; } x;
    x.u.x = (uint32_t)f2bf(lo.x) | ((uint32_t)f2bf(lo.y) << 16);
    x.u.y = (uint32_t)f2bf(lo.z) | ((uint32_t)f2bf(lo.w) << 16);
    x.u.z = (uint32_t)f2bf(hi.x) | ((uint32_t)f2bf(hi.y) << 16);
    x.u.w = (uint32_t)f2bf(hi.z) | ((uint32_t)f2bf(hi.w) << 16);
    return x.v;
}
// async global->LDS, 16B per lane; LDS dest = wave-uniform base + lane*16
DI void gl_lds16(const void* g, void* l) {
    __builtin_amdgcn_global_load_lds(
        (__attribute__((address_space(1))) void*)(uintptr_t)g,
        (__attribute__((address_space(3))) void*)(uintptr_t)l,
        16, 0, 0);
}

// ---------------- kernel 0: zero ce acc + Wc^T bf16 (pad 31->32) ----------
__global__ void k_init(const float* __restrict__ Wc, uint16_t* __restrict__ WcT,
                       float* __restrict__ accs) {
    int tid = threadIdx.x;
    if (tid < 4) accs[tid] = 0.f;
    for (int idx = tid; idx < 32 * 256; idx += 256) {
        int n = idx >> 8, k = idx & 255;
        WcT[idx] = (n < 31) ? f2bf(Wc[k * 31 + n]) : (uint16_t)0;
    }
}

// ---------------- kernel 1: Wb [2048][256] -> WbT bf16 [256][2048] --------
__global__ void k_transpose_wb(const float* __restrict__ Wb, uint16_t* __restrict__ WbT) {
    __shared__ float t[32][33];
    int kb = blockIdx.x, nb = blockIdx.y;
    int tx = threadIdx.x & 31, ty0 = (threadIdx.x >> 5) * 4;
    for (int i = 0; i < 4; ++i)
        t[ty0 + i][tx] = Wb[(kb * 32 + ty0 + i) * 256 + nb * 32 + tx];
    __syncthreads();
    for (int i = 0; i < 4; ++i)
        WbT[(nb * 32 + ty0 + i) * 2048 + kb * 32 + tx] = f2bf(t[tx][ty0 + i]);
}

// ---------------- kernel 2: Y = relu([src;tar] @ Wb + bb), bf16 out -------
// Barrier-free main loop: block = 32 rows x N=256 full, 8 waves split K
// (256 each = 8 steps of 32). MFMA fragments loaded DIRECTLY from global
// (A: coalesced fp32->bf16 in reg, depth-2 prefetch; B: L2-hot WbT).
// Cross-wave K-reduction via LDS at the end (4 small rounds).
__launch_bounds__(512, 2)
__global__ void k_bottleneck(const float* __restrict__ src, const float* __restrict__ tgt,
                             const uint16_t* __restrict__ WbT, const float* __restrict__ bb,
                             uint16_t* __restrict__ Y) {
    __shared__ float red[8][2048];    // 64 KB: 8 partials x (8 rows x 256 cols)
    int tid = threadIdx.x, lane = tid & 63, w = tid >> 6;   // w = K-slice 0..7
    int m0 = blockIdx.x * 32;
    const float* X = (m0 < 4096) ? (src + (size_t)m0 * 2048)
                                 : (tgt + (size_t)(m0 - 4096) * 2048);
    int fr = lane & 15;        // frag row/col within 16
    int kq = lane >> 4;        // k-quad 0..3
    const float* Ag = X + (size_t)fr * 2048 + w * 256 + kq * 8;
    const uint16_t* Bg = WbT + (size_t)fr * 2048 + w * 256 + kq * 8;

    f32x4 acc[2][16] = {};     // [mi (16-row block)][nf (16-col block)]

    // A register prefetch, depth 2: [step parity][mi][half]
    float4 aA[2][2][2];
    #pragma unroll
    for (int mi = 0; mi < 2; ++mi) {
        aA[0][mi][0] = *(const float4*)(Ag + mi * 32768);
        aA[0][mi][1] = *(const float4*)(Ag + mi * 32768 + 4);
        aA[1][mi][0] = *(const float4*)(Ag + mi * 32768 + 32);
        aA[1][mi][1] = *(const float4*)(Ag + mi * 32768 + 36);
    }
    #pragma unroll
    for (int t = 0; t < 8; ++t) {
        bf16x8 af[2];
        #pragma unroll
        for (int mi = 0; mi < 2; ++mi)
            af[mi] = cvt8(aA[t & 1][mi][0], aA[t & 1][mi][1]);
        if (t < 6) {   // prefetch A(t+2) into the slot just consumed
            #pragma unroll
            for (int mi = 0; mi < 2; ++mi) {
                aA[t & 1][mi][0] = *(const float4*)(Ag + mi * 32768 + (t + 2) * 32);
                aA[t & 1][mi][1] = *(const float4*)(Ag + mi * 32768 + (t + 2) * 32 + 4);
            }
        }
        #pragma unroll
        for (int nf = 0; nf < 16; ++nf) {
            bf16x8 bv = *(const bf16x8*)(Bg + (size_t)nf * 32768 + t * 32);
            acc[0][nf] = __builtin_amdgcn_mfma_f32_16x16x32_bf16(af[0], bv, acc[0][nf], 0, 0, 0);
            acc[1][nf] = __builtin_amdgcn_mfma_f32_16x16x32_bf16(af[1], bv, acc[1][nf], 0, 0, 0);
        }
    }

    // ---- cross-wave reduction: 4 rounds of 8 rows x 256 cols ----
    int e0 = tid * 4;            // 0..2044: output index within a round
    int rl = e0 >> 8;            // local row 0..7
    int col = e0 & 255;
    float4 bias = *(const float4*)(bb + col);
    #pragma unroll
    for (int mi = 0; mi < 2; ++mi) {
        #pragma unroll
        for (int half = 0; half < 2; ++half) {
            if (mi || half) __syncthreads();   // protect red reuse
            if ((kq >> 1) == half) {           // this lane's rows are in this half
                #pragma unroll
                for (int nf = 0; nf < 16; ++nf)
                    #pragma unroll
                    for (int j = 0; j < 4; ++j)
                        red[w][((kq & 1) * 4 + j) * 256 + nf * 16 + fr] = acc[mi][nf][j];
            }
            __syncthreads();
            float4 s = {0.f, 0.f, 0.f, 0.f};
            #pragma unroll
            for (int p = 0; p < 8; ++p) {
                float4 v = *(const float4*)(&red[p][e0]);
                s.x += v.x; s.y += v.y; s.z += v.z; s.w += v.w;
            }
            int row = m0 + mi * 16 + half * 8 + rl;
            ushort4 o;
            o.x = f2bf(fmaxf(s.x + bias.x, 0.f));
            o.y = f2bf(fmaxf(s.y + bias.y, 0.f));
            o.z = f2bf(fmaxf(s.z + bias.z, 0.f));
            o.w = f2bf(fmaxf(s.w + bias.w, 0.f));
            *(ushort4*)(Y + (size_t)row * 256 + col) = o;
        }
    }
}

// ---------------- kernel 3: fused row sum-of-squares + column partials ----
// single pass over Y; grid 256 blocks x 32 rows; colsum_part is [256][256]
__launch_bounds__(256)
__global__ void k_stats(const uint16_t* __restrict__ Y, float* __restrict__ s2t2,
                        float* __restrict__ colsum_part) {
    __shared__ float cs[4][256];
    int tid = threadIdx.x, lane = tid & 63, w = tid >> 6;
    int r0 = blockIdx.x * 32 + w * 8;
    float c0 = 0.f, c1 = 0.f, c2 = 0.f, c3 = 0.f;
    for (int i = 0; i < 8; ++i) {
        int row = r0 + i;
        ushort4 v = *(const ushort4*)(Y + (size_t)row * 256 + lane * 4);
        float a = bf2f(v.x), b = bf2f(v.y), c = bf2f(v.z), d = bf2f(v.w);
        c0 += a; c1 += b; c2 += c; c3 += d;
        float s = a * a + b * b + c * c + d * d;
        for (int m = 1; m < 64; m <<= 1) s += __shfl_xor(s, m);
        if (lane == 0) s2t2[row] = s;
    }
    cs[w][lane * 4 + 0] = c0;
    cs[w][lane * 4 + 1] = c1;
    cs[w][lane * 4 + 2] = c2;
    cs[w][lane * 4 + 3] = c3;
    __syncthreads();
    colsum_part[blockIdx.x * 256 + tid] =
        cs[0][tid] + cs[1][tid] + cs[2][tid] + cs[3][tid];
}

// ---------------- kernel 5: classifier + softmax margins + CE -----------
__launch_bounds__(256)
__global__ void k_classifier(const uint16_t* __restrict__ Y, const uint16_t* __restrict__ WcT,
                             const float* __restrict__ bc, const int* __restrict__ labels,
                             float* __restrict__ out_margin, float* __restrict__ ce_acc) {
    __shared__ __align__(16) uint8_t lds[49152];  // A 32KB @0, B 16KB @32768
    int tid = threadIdx.x, lane = tid & 63, w = tid >> 6;
    int m0 = blockIdx.x * 64;
    int cc = (lane >> 4) ^ (lane & 3) ^ ((lane >> 2) & 3);
    for (int s = w; s < 48; s += 4) {
        int r, p, c;
        if (s < 32) {
            int kb = s >> 2, r0 = (s & 3) * 16;
            r = r0 + (lane >> 2); p = lane & 3;
            c = p ^ (r & 3) ^ ((r >> 2) & 3);
            gl_lds16(Y + (size_t)(m0 + r) * 256 + kb * 32 + c * 8, lds + s * 1024);
        } else {
            int s2 = s - 32;
            int kb = s2 >> 1, r0 = (s2 & 1) * 16;
            r = r0 + (lane >> 2); p = lane & 3;
            c = p ^ (r & 3) ^ ((r >> 2) & 3);
            gl_lds16(WcT + r * 256 + kb * 32 + c * 8, lds + 32768 + s2 * 1024);
        }
    }
    __syncthreads();
    f32x4 acc[2] = {};
    for (int kb = 0; kb < 8; ++kb) {
        int r = w * 16 + (lane & 15);
        bf16x8 a = *(const bf16x8*)(lds + kb * 4096 + r * 64 + cc * 16);
        for (int nf = 0; nf < 2; ++nf) {
            int rn = nf * 16 + (lane & 15);
            bf16x8 b = *(const bf16x8*)(lds + 32768 + kb * 2048 + rn * 64 + cc * 16);
            acc[nf] = __builtin_amdgcn_mfma_f32_16x16x32_bf16(a, b, acc[nf], 0, 0, 0);
        }
    }
    int c0 = lane & 15, c1 = 16 + c0;
    float bc0 = bc[c0];
    float bc1 = (c1 < 31) ? bc[c1] : 0.f;
    bool is_src = (m0 < 4096);
    float ce_local = 0.f;
    for (int j = 0; j < 4; ++j) {
        int row = m0 + w * 16 + (lane >> 4) * 4 + j;
        float v0 = acc[0][j] + bc0;
        float v1 = (c1 < 31) ? (acc[1][j] + bc1) : -1e30f;
        float mx = fmaxf(v0, v1);
        for (int m = 1; m < 16; m <<= 1) mx = fmaxf(mx, __shfl_xor(mx, m, 16));
        float e0 = __expf(v0 - mx);
        float e1 = (c1 < 31) ? __expf(v1 - mx) : 0.f;
        float ssum = e0 + e1;
        for (int m = 1; m < 16; m <<= 1) ssum += __shfl_xor(ssum, m, 16);
        float inv = 1.f / ssum;
        float conf0 = e0 * inv, conf1 = e1 * inv;
        int lab;
        if (is_src) {
            lab = labels[row];
        } else {
            float bv; int bi;
            if (v0 >= v1) { bv = v0; bi = c0; } else { bv = v1; bi = c1; }
            for (int m = 1; m < 16; m <<= 1) {
                float ov = __shfl_xor(bv, m, 16);
                int oi = __shfl_xor(bi, m, 16);
                if (ov > bv || (ov == bv && oi < bi)) { bv = ov; bi = oi; }
            }
            lab = bi;
        }
        float tc = (c0 == lab ? conf0 : 0.f) + (c1 == lab ? conf1 : 0.f);
        for (int m = 1; m < 16; m <<= 1) tc += __shfl_xor(tc, m, 16);
        float ex = fmaxf(c0 == lab ? -1.f : conf0,
                         (c1 == lab || c1 >= 31) ? -1.f : conf1);
        for (int m = 1; m < 16; m <<= 1) ex = fmaxf(ex, __shfl_xor(ex, m, 16));
        if (c0 == 0) out_margin[row] = tc - ex;
        if (is_src) {
            float vl = (c0 == lab) ? v0 : ((c1 == lab) ? v1 : -1e30f);
            for (int m = 1; m < 16; m <<= 1) vl = fmaxf(vl, __shfl_xor(vl, m, 16));
            if (c0 == 0) ce_local += -(vl - mx - __logf(ssum));
        }
    }
    if (is_src) {
        ce_local += __shfl_xor(ce_local, 16);
        ce_local += __shfl_xor(ce_local, 32);
        if (lane == 0) atomicAdd(ce_acc, ce_local);   // 64 atomics total: fine
    }
}

// ---------------- kernel 6: pairwise d2 -> exp partial sums (no atomics) -
// 128x128 tile, K=256 staged in 2 halves of 64KB LDS
__launch_bounds__(256)
__global__ void k_pairwise(const uint16_t* __restrict__ Y, const float* __restrict__ s2t2,
                           float* __restrict__ gk_part) {
    __shared__ __align__(16) uint8_t lds[65536];  // A 32KB @0, B 32KB @32768
    int tid = threadIdx.x, lane = tid & 63, w = tid >> 6;
    int m0 = blockIdx.x * 128, n0 = blockIdx.y * 128;
    int cc = (lane >> 4) ^ (lane & 3) ^ ((lane >> 2) & 3);
    int wm = (w & 1) * 64, wn = (w >> 1) * 64;
    f32x4 acc[4][4] = {};
    for (int h = 0; h < 2; ++h) {
        if (h) __syncthreads();
        int k0 = h * 128;
        for (int i = 0; i < 8; ++i) {
            int s = w * 8 + i;
            int kb = s >> 3, r0 = (s & 7) * 16;
            int r = r0 + (lane >> 2), p = lane & 3;
            int c = p ^ (r & 3) ^ ((r >> 2) & 3);
            gl_lds16(Y + (size_t)(m0 + r) * 256 + k0 + kb * 32 + c * 8, lds + s * 1024);
            gl_lds16(Y + (size_t)(4096 + n0 + r) * 256 + k0 + kb * 32 + c * 8,
                     lds + 32768 + s * 1024);
        }
        __syncthreads();
        for (int kb = 0; kb < 4; ++kb) {
            bf16x8 a[4], b[4];
            for (int mi = 0; mi < 4; ++mi) {
                int r = wm + mi * 16 + (lane & 15);
                a[mi] = *(const bf16x8*)(lds + kb * 8192 + r * 64 + cc * 16);
            }
            for (int nf = 0; nf < 4; ++nf) {
                int rn = wn + nf * 16 + (lane & 15);
                b[nf] = *(const bf16x8*)(lds + 32768 + kb * 8192 + rn * 64 + cc * 16);
            }
            for (int mi = 0; mi < 4; ++mi)
                for (int nf = 0; nf < 4; ++nf)
                    acc[mi][nf] = __builtin_amdgcn_mfma_f32_16x16x32_bf16(
                        a[mi], b[nf], acc[mi][nf], 0, 0, 0);
        }
    }
    float t2v[4];
    for (int nf = 0; nf < 4; ++nf)
        t2v[nf] = s2t2[4096 + n0 + wn + nf * 16 + (lane & 15)];
    float g1 = 0.f, g5 = 0.f;
    for (int mi = 0; mi < 4; ++mi) {
        int rbase = m0 + wm + mi * 16 + (lane >> 4) * 4;
        float s2v[4];
        for (int j = 0; j < 4; ++j) s2v[j] = s2t2[rbase + j];
        for (int nf = 0; nf < 4; ++nf)
            for (int j = 0; j < 4; ++j) {
                float d2 = s2v[j] + t2v[nf] - 2.f * acc[mi][nf][j];
                d2 = fmaxf(d2, 0.f);
                g1 += __expf(-0.5f * d2);
                g5 += __expf(-0.02f * d2);
            }
    }
    for (int m = 1; m < 64; m <<= 1) { g1 += __shfl_xor(g1, m); g5 += __shfl_xor(g5, m); }
    // block-level reduce (reuse LDS), one plain store per block
    __syncthreads();
    float* red = (float*)lds;
    if (lane == 0) { red[w * 2] = g1; red[w * 2 + 1] = g5; }
    __syncthreads();
    if (tid == 0) {
        int bid = blockIdx.y * 32 + blockIdx.x;
        gk_part[bid * 2]     = red[0] + red[2] + red[4] + red[6];
        gk_part[bid * 2 + 1] = red[1] + red[3] + red[5] + red[7];
    }
}

// ---------------- kernel 7: finalize scalars ----------------------------
__global__ void k_finalize(const float* __restrict__ colsum_part,
                           const float* __restrict__ gk_part,
                           const float* __restrict__ accs, float* __restrict__ d_out) {
    __shared__ float red[12];
    int tid = threadIdx.x, lane = tid & 63, w = tid >> 6;
    float cs = 0.f, ct = 0.f;
    for (int b = 0; b < 128; ++b)   cs += colsum_part[b * 256 + tid];
    for (int b = 128; b < 256; ++b) ct += colsum_part[b * 256 + tid];
    float delta = (cs - ct) * (1.f / 4096.f);
    float sq = delta * delta;
    float g1 = 0.f, g5 = 0.f;
    for (int i = 0; i < 4; ++i) {
        int p = tid * 4 + i;
        g1 += gk_part[p * 2];
        g5 += gk_part[p * 2 + 1];
    }
    for (int m = 1; m < 64; m <<= 1) {
        sq += __shfl_xor(sq, m);
        g1 += __shfl_xor(g1, m);
        g5 += __shfl_xor(g5, m);
    }
    if (lane == 0) { red[w * 3] = sq; red[w * 3 + 1] = g1; red[w * 3 + 2] = g5; }
    __syncthreads();
    if (tid == 0) {
        d_out[0] = accs[0] * (1.f / 4096.f);
        d_out[1] = red[0] + red[3] + red[6] + red[9];
        d_out[2] = (red[1] + red[4] + red[7] + red[10]) * 5.9604644775390625e-08f;
        d_out[3] = (red[2] + red[5] + red[8] + red[11]) * 5.9604644775390625e-08f;
    }
}

extern "C" void kernel_launch(void* const* d_in, const int* in_sizes, int n_in,
                              void* d_out, int out_size, void* d_ws, size_t ws_size,
                              hipStream_t stream) {
    const float* source = (const float*)d_in[0];
    const float* target = (const float*)d_in[1];
    const float* Wb     = (const float*)d_in[2];
    const float* bb     = (const float*)d_in[3];
    const float* Wc     = (const float*)d_in[4];
    const float* bc     = (const float*)d_in[5];
    const int*   labels = (const int*)d_in[6];
    float* out = (float*)d_out;
    uint8_t* ws = (uint8_t*)d_ws;

    uint16_t* Y    = (uint16_t*)(ws);                 // 8192*256*2 = 4 MB
    uint16_t* WbT  = (uint16_t*)(ws + 4194304);       // 1 MB (dead after k_bottleneck)
    uint16_t* WcT  = (uint16_t*)(ws + 5242880);       // 16 KB
    float*    s2t2 = (float*)(ws + 5259264);          // 32 KB
    float*    accs = (float*)(ws + 5292032);          // [ce, pad...]
    // alias the dead WbT region (only read by k_bottleneck, which runs first):
    float*    colsum_part = (float*)(ws + 4194304);             // 256*256 fl = 256 KB
    float*    gk_part     = (float*)(ws + 4194304 + 262144);    // 1024*2 fl = 8 KB

    k_init<<<1, 256, 0, stream>>>(Wc, WcT, accs);
    k_transpose_wb<<<dim3(64, 8), 256, 0, stream>>>(Wb, WbT);
    k_bottleneck<<<256, 512, 0, stream>>>(source, target, WbT, bb, Y);
    k_stats<<<256, 256, 0, stream>>>(Y, s2t2, colsum_part);
    k_classifier<<<128, 256, 0, stream>>>(Y, WcT, bc, labels, out + 4, accs);
    k_pairwise<<<dim3(32, 32), 256, 0, stream>>>(Y, s2t2, gk_part);
    k_finalize<<<1, 256, 0, stream>>>(colsum_part, gk_part, accs, out);
}

// Round 6
// 175.695 us; speedup vs baseline: 1.0865x; 1.0865x over previous
//
#include <hip/hip_runtime.h>
#include <stdint.h>

#define DI __device__ __forceinline__

typedef float f32x4 __attribute__((ext_vector_type(4)));
typedef short bf16x8 __attribute__((ext_vector_type(8)));

DI uint16_t f2bf(float f) {
    union { float f; uint32_t u; } v; v.f = f;
    uint32_t r = v.u + 0x7FFF + ((v.u >> 16) & 1);
    return (uint16_t)(r >> 16);
}
DI float bf2f(uint16_t h) {
    union { uint32_t u; float f; } v; v.u = ((uint32_t)h) << 16;
    return v.f;
}
// async global->LDS, 16B per lane; LDS dest = wave-uniform base + lane*16
DI void gl_lds16(const void* g, void* l) {
    __builtin_amdgcn_global_load_lds(
        (__attribute__((address_space(1))) void*)(uintptr_t)g,
        (__attribute__((address_space(3))) void*)(uintptr_t)l,
        16, 0, 0);
}

// ---------------- kernel 0: zero ce acc + Wc^T bf16 (pad 31->32) ----------
__global__ void k_init(const float* __restrict__ Wc, uint16_t* __restrict__ WcT,
                       float* __restrict__ accs) {
    int tid = threadIdx.x;
    if (tid < 4) accs[tid] = 0.f;
    for (int idx = tid; idx < 32 * 256; idx += 256) {
        int n = idx >> 8, k = idx & 255;
        WcT[idx] = (n < 31) ? f2bf(Wc[k * 31 + n]) : (uint16_t)0;
    }
}

// ---------------- kernel 1: Wb [2048][256] -> WbT bf16 [256][2048] --------
__global__ void k_transpose_wb(const float* __restrict__ Wb, uint16_t* __restrict__ WbT) {
    __shared__ float t[32][33];
    int kb = blockIdx.x, nb = blockIdx.y;
    int tx = threadIdx.x & 31, ty0 = (threadIdx.x >> 5) * 4;
    for (int i = 0; i < 4; ++i)
        t[ty0 + i][tx] = Wb[(kb * 32 + ty0 + i) * 256 + nb * 32 + tx];
    __syncthreads();
    for (int i = 0; i < 4; ++i)
        WbT[(nb * 32 + ty0 + i) * 2048 + kb * 32 + tx] = f2bf(t[tx][ty0 + i]);
}

// ---------------- kernel 2: Y = relu([src;tar] @ Wb + bb), bf16 out -------
// tile 32(m) x 128(n), BK=64, grid 512 -> 2 blocks/CU.
// B: 3-buffer LDS ring staged TWO iterations ahead (full-iteration slack on
// the end-of-iter vmcnt). A: 2-deep register prefetch. One vmcnt(6) +
// lgkm0+barrier per iteration; waits only on loads issued a full iter ago.
__launch_bounds__(256)
__global__ void k_bottleneck(const float* __restrict__ src, const float* __restrict__ tgt,
                             const uint16_t* __restrict__ WbT, const float* __restrict__ bb,
                             uint16_t* __restrict__ Y) {
    // LA[2]: 4KB @0, @4096 ; LB[3]: 16KB @8192, @24576, @40960
    __shared__ __align__(16) uint8_t lds[57344];
    int tid = threadIdx.x;
    int lane = tid & 63, w = tid >> 6;
    int bm = blockIdx.x >> 1, bn = blockIdx.x & 1;   // N-halves of same A adjacent
    int m0 = bm * 32;
    const float* X = (m0 < 4096) ? (src + (size_t)m0 * 2048)
                                 : (tgt + (size_t)(m0 - 4096) * 2048);
    // A-staging assignment: 8 fp32 per thread
    int ar = tid >> 3, akb = (tid >> 2) & 1, ap = tid & 3;
    int ac = ap ^ (ar & 3) ^ ((ar >> 2) & 3);
    const float* Ag = X + ar * 2048 + akb * 32 + ac * 8;
    const int AwOff = akb * 2048 + ar * 64 + ap * 16;
    int cc = (lane >> 4) ^ (lane & 3) ^ ((lane >> 2) & 3);
    // B-stage per-thread global bases (4 segments/wave of 1KB)
    const uint16_t* Bg0; const uint16_t* Bg1; const uint16_t* Bg2; const uint16_t* Bg3;
    {
        int p = lane & 3;
        int i0 = w * 4;
        #define BGADDR(ii) ({ int s_ = i0 + (ii); int kb_ = s_ >> 3; \
            int r_ = (s_ & 7) * 16 + (lane >> 2); \
            int c_ = p ^ (r_ & 3) ^ ((r_ >> 2) & 3); \
            WbT + (size_t)(bn * 128 + r_) * 2048 + kb_ * 32 + c_ * 8; })
        Bg0 = BGADDR(0); Bg1 = BGADDR(1); Bg2 = BGADDR(2); Bg3 = BGADDR(3);
        #undef BGADDR
    }
    const int lbB = 8192 + w * 4096;   // this wave's 4 segs within an LB buffer

    f32x4 acc[2][2] = {};
    float4 rE0, rE1, rO0, rO1;

    #define STAGE_B(buf, k0) do { \
        gl_lds16(Bg0 + (k0), lds + lbB + (buf) * 16384 + 0);    \
        gl_lds16(Bg1 + (k0), lds + lbB + (buf) * 16384 + 1024); \
        gl_lds16(Bg2 + (k0), lds + lbB + (buf) * 16384 + 2048); \
        gl_lds16(Bg3 + (k0), lds + lbB + (buf) * 16384 + 3072); \
    } while (0)

    #define WRITE_A(par, r0v, r1v) do { \
        uint4 u_; \
        u_.x = (uint32_t)f2bf((r0v).x) | ((uint32_t)f2bf((r0v).y) << 16); \
        u_.y = (uint32_t)f2bf((r0v).z) | ((uint32_t)f2bf((r0v).w) << 16); \
        u_.z = (uint32_t)f2bf((r1v).x) | ((uint32_t)f2bf((r1v).y) << 16); \
        u_.w = (uint32_t)f2bf((r1v).z) | ((uint32_t)f2bf((r1v).w) << 16); \
        *(uint4*)(lds + (par) * 4096 + AwOff) = u_; \
    } while (0)

    #define COMPUTE(buf, par) do { \
        _Pragma("unroll") \
        for (int kb = 0; kb < 2; ++kb) { \
            bf16x8 a_[2], b_[2]; \
            _Pragma("unroll") \
            for (int mi = 0; mi < 2; ++mi) \
                a_[mi] = *(const bf16x8*)(lds + (par) * 4096 + kb * 2048 + \
                                          (mi * 16 + (lane & 15)) * 64 + cc * 16); \
            _Pragma("unroll") \
            for (int nf = 0; nf < 2; ++nf) \
                b_[nf] = *(const bf16x8*)(lds + 8192 + (buf) * 16384 + kb * 8192 + \
                                          (w * 32 + nf * 16 + (lane & 15)) * 64 + cc * 16); \
            _Pragma("unroll") \
            for (int mi = 0; mi < 2; ++mi) \
                _Pragma("unroll") \
                for (int nf = 0; nf < 2; ++nf) \
                    acc[mi][nf] = __builtin_amdgcn_mfma_f32_16x16x32_bf16( \
                        a_[mi], b_[nf], acc[mi][nf], 0, 0, 0); \
        } \
    } while (0)

    #define FENCE() asm volatile("" ::: "memory")
    #define WAIT6() asm volatile("s_waitcnt vmcnt(6)" ::: "memory")
    #define WAIT0() asm volatile("s_waitcnt vmcnt(0)" ::: "memory")
    #define LGKM0_BAR() do { asm volatile("s_waitcnt lgkmcnt(0)" ::: "memory"); \
                             __builtin_amdgcn_s_barrier(); } while (0)

    // ---- prologue: queue = [B0(4), A0(2), B1(4), A1(2)] ----
    STAGE_B(0, 0);
    FENCE();
    rE0 = *(const float4*)(Ag);                      // A(0)
    rE1 = *(const float4*)(Ag + 4);
    FENCE();
    STAGE_B(1, 64);
    FENCE();
    rO0 = *(const float4*)(Ag + 64);                 // A(1)
    rO1 = *(const float4*)(Ag + 68);
    WAIT6();                                         // drains B0+A0; B1,A1 in flight
    WRITE_A(0, rE0, rE1);
    LGKM0_BAR();

    // ---- main loop t = 0..29 (6-unrolled: ring%3 x parity%2) ----
    // invariant at iter t entry: outstanding = [B(t+1) 4, A(t+1) 2]
    #define ITER(tc, BUF, NBUF, RL0, RL1, RW0, RW1, WPAR) do { \
        STAGE_B(NBUF, ((tc) + 2) * 64);  /* B(t+2), 2 iters ahead */ \
        FENCE(); \
        RL0 = *(const float4*)(Ag + ((tc) + 2) * 64); \
        RL1 = *(const float4*)(Ag + ((tc) + 2) * 64 + 4); \
        FENCE(); \
        COMPUTE(BUF, (tc) & 1); \
        WAIT6(); /* drains B(t+1)+A(t+1) (issued a full iter ago) */ \
        WRITE_A(WPAR, RW0, RW1); \
        LGKM0_BAR(); \
    } while (0)

    for (int t6 = 0; t6 < 5; ++t6) {
        int tb = t6 * 6;
        ITER(tb + 0, 0, 2, rE0, rE1, rO0, rO1, 1);
        ITER(tb + 1, 1, 0, rO0, rO1, rE0, rE1, 0);
        ITER(tb + 2, 2, 1, rE0, rE1, rO0, rO1, 1);
        ITER(tb + 3, 0, 2, rO0, rO1, rE0, rE1, 0);
        ITER(tb + 4, 1, 0, rE0, rE1, rO0, rO1, 1);
        ITER(tb + 5, 2, 1, rO0, rO1, rE0, rE1, 0);
    }
    // ---- t = 30: outstanding = [B31(4), A31(2)]; no new issues ----
    COMPUTE(0, 0);
    WAIT0();
    WRITE_A(1, rO0, rO1);                            // A(31) -> LA[1]
    LGKM0_BAR();
    // ---- t = 31 ----
    COMPUTE(1, 1);

    #undef ITER
    #undef STAGE_B
    #undef WRITE_A
    #undef COMPUTE
    #undef FENCE
    #undef WAIT6
    #undef WAIT0
    #undef LGKM0_BAR

    for (int mi = 0; mi < 2; ++mi)
        for (int nf = 0; nf < 2; ++nf) {
            int col = bn * 128 + w * 32 + nf * 16 + (lane & 15);
            float bias = bb[col];
            for (int j = 0; j < 4; ++j) {
                int row = m0 + mi * 16 + (lane >> 4) * 4 + j;
                float v = acc[mi][nf][j] + bias;
                v = fmaxf(v, 0.f);
                Y[(size_t)row * 256 + col] = f2bf(v);
            }
        }
}

// ---------------- kernel 3: fused row sum-of-squares + column partials ----
// single pass over Y; grid 256 blocks x 32 rows; colsum_part is [256][256]
__launch_bounds__(256)
__global__ void k_stats(const uint16_t* __restrict__ Y, float* __restrict__ s2t2,
                        float* __restrict__ colsum_part) {
    __shared__ float cs[4][256];
    int tid = threadIdx.x, lane = tid & 63, w = tid >> 6;
    int r0 = blockIdx.x * 32 + w * 8;
    float c0 = 0.f, c1 = 0.f, c2 = 0.f, c3 = 0.f;
    for (int i = 0; i < 8; ++i) {
        int row = r0 + i;
        ushort4 v = *(const ushort4*)(Y + (size_t)row * 256 + lane * 4);
        float a = bf2f(v.x), b = bf2f(v.y), c = bf2f(v.z), d = bf2f(v.w);
        c0 += a; c1 += b; c2 += c; c3 += d;
        float s = a * a + b * b + c * c + d * d;
        for (int m = 1; m < 64; m <<= 1) s += __shfl_xor(s, m);
        if (lane == 0) s2t2[row] = s;
    }
    cs[w][lane * 4 + 0] = c0;
    cs[w][lane * 4 + 1] = c1;
    cs[w][lane * 4 + 2] = c2;
    cs[w][lane * 4 + 3] = c3;
    __syncthreads();
    colsum_part[blockIdx.x * 256 + tid] =
        cs[0][tid] + cs[1][tid] + cs[2][tid] + cs[3][tid];
}

// ---------------- kernel 5: classifier + softmax margins + CE -----------
__launch_bounds__(256)
__global__ void k_classifier(const uint16_t* __restrict__ Y, const uint16_t* __restrict__ WcT,
                             const float* __restrict__ bc, const int* __restrict__ labels,
                             float* __restrict__ out_margin, float* __restrict__ ce_acc) {
    __shared__ __align__(16) uint8_t lds[49152];  // A 32KB @0, B 16KB @32768
    int tid = threadIdx.x, lane = tid & 63, w = tid >> 6;
    int m0 = blockIdx.x * 64;
    int cc = (lane >> 4) ^ (lane & 3) ^ ((lane >> 2) & 3);
    for (int s = w; s < 48; s += 4) {
        int r, p, c;
        if (s < 32) {
            int kb = s >> 2, r0 = (s & 3) * 16;
            r = r0 + (lane >> 2); p = lane & 3;
            c = p ^ (r & 3) ^ ((r >> 2) & 3);
            gl_lds16(Y + (size_t)(m0 + r) * 256 + kb * 32 + c * 8, lds + s * 1024);
        } else {
            int s2 = s - 32;
            int kb = s2 >> 1, r0 = (s2 & 1) * 16;
            r = r0 + (lane >> 2); p = lane & 3;
            c = p ^ (r & 3) ^ ((r >> 2) & 3);
            gl_lds16(WcT + r * 256 + kb * 32 + c * 8, lds + 32768 + s2 * 1024);
        }
    }
    __syncthreads();
    f32x4 acc[2] = {};
    for (int kb = 0; kb < 8; ++kb) {
        int r = w * 16 + (lane & 15);
        bf16x8 a = *(const bf16x8*)(lds + kb * 4096 + r * 64 + cc * 16);
        for (int nf = 0; nf < 2; ++nf) {
            int rn = nf * 16 + (lane & 15);
            bf16x8 b = *(const bf16x8*)(lds + 32768 + kb * 2048 + rn * 64 + cc * 16);
            acc[nf] = __builtin_amdgcn_mfma_f32_16x16x32_bf16(a, b, acc[nf], 0, 0, 0);
        }
    }
    int c0 = lane & 15, c1 = 16 + c0;
    float bc0 = bc[c0];
    float bc1 = (c1 < 31) ? bc[c1] : 0.f;
    bool is_src = (m0 < 4096);
    float ce_local = 0.f;
    for (int j = 0; j < 4; ++j) {
        int row = m0 + w * 16 + (lane >> 4) * 4 + j;
        float v0 = acc[0][j] + bc0;
        float v1 = (c1 < 31) ? (acc[1][j] + bc1) : -1e30f;
        float mx = fmaxf(v0, v1);
        for (int m = 1; m < 16; m <<= 1) mx = fmaxf(mx, __shfl_xor(mx, m, 16));
        float e0 = __expf(v0 - mx);
        float e1 = (c1 < 31) ? __expf(v1 - mx) : 0.f;
        float ssum = e0 + e1;
        for (int m = 1; m < 16; m <<= 1) ssum += __shfl_xor(ssum, m, 16);
        float inv = 1.f / ssum;
        float conf0 = e0 * inv, conf1 = e1 * inv;
        int lab;
        if (is_src) {
            lab = labels[row];
        } else {
            float bv; int bi;
            if (v0 >= v1) { bv = v0; bi = c0; } else { bv = v1; bi = c1; }
            for (int m = 1; m < 16; m <<= 1) {
                float ov = __shfl_xor(bv, m, 16);
                int oi = __shfl_xor(bi, m, 16);
                if (ov > bv || (ov == bv && oi < bi)) { bv = ov; bi = oi; }
            }
            lab = bi;
        }
        float tc = (c0 == lab ? conf0 : 0.f) + (c1 == lab ? conf1 : 0.f);
        for (int m = 1; m < 16; m <<= 1) tc += __shfl_xor(tc, m, 16);
        float ex = fmaxf(c0 == lab ? -1.f : conf0,
                         (c1 == lab || c1 >= 31) ? -1.f : conf1);
        for (int m = 1; m < 16; m <<= 1) ex = fmaxf(ex, __shfl_xor(ex, m, 16));
        if (c0 == 0) out_margin[row] = tc - ex;
        if (is_src) {
            float vl = (c0 == lab) ? v0 : ((c1 == lab) ? v1 : -1e30f);
            for (int m = 1; m < 16; m <<= 1) vl = fmaxf(vl, __shfl_xor(vl, m, 16));
            if (c0 == 0) ce_local += -(vl - mx - __logf(ssum));
        }
    }
    if (is_src) {
        ce_local += __shfl_xor(ce_local, 16);
        ce_local += __shfl_xor(ce_local, 32);
        if (lane == 0) atomicAdd(ce_acc, ce_local);   // 64 atomics total: fine
    }
}

// ---------------- kernel 6: pairwise d2 -> exp partial sums (no atomics) -
// 128x128 tile, K=256 staged in 2 halves of 64KB LDS
__launch_bounds__(256)
__global__ void k_pairwise(const uint16_t* __restrict__ Y, const float* __restrict__ s2t2,
                           float* __restrict__ gk_part) {
    __shared__ __align__(16) uint8_t lds[65536];  // A 32KB @0, B 32KB @32768
    int tid = threadIdx.x, lane = tid & 63, w = tid >> 6;
    int m0 = blockIdx.x * 128, n0 = blockIdx.y * 128;
    int cc = (lane >> 4) ^ (lane & 3) ^ ((lane >> 2) & 3);
    int wm = (w & 1) * 64, wn = (w >> 1) * 64;
    f32x4 acc[4][4] = {};
    for (int h = 0; h < 2; ++h) {
        if (h) __syncthreads();
        int k0 = h * 128;
        for (int i = 0; i < 8; ++i) {
            int s = w * 8 + i;
            int kb = s >> 3, r0 = (s & 7) * 16;
            int r = r0 + (lane >> 2), p = lane & 3;
            int c = p ^ (r & 3) ^ ((r >> 2) & 3);
            gl_lds16(Y + (size_t)(m0 + r) * 256 + k0 + kb * 32 + c * 8, lds + s * 1024);
            gl_lds16(Y + (size_t)(4096 + n0 + r) * 256 + k0 + kb * 32 + c * 8,
                     lds + 32768 + s * 1024);
        }
        __syncthreads();
        for (int kb = 0; kb < 4; ++kb) {
            bf16x8 a[4], b[4];
            for (int mi = 0; mi < 4; ++mi) {
                int r = wm + mi * 16 + (lane & 15);
                a[mi] = *(const bf16x8*)(lds + kb * 8192 + r * 64 + cc * 16);
            }
            for (int nf = 0; nf < 4; ++nf) {
                int rn = wn + nf * 16 + (lane & 15);
                b[nf] = *(const bf16x8*)(lds + 32768 + kb * 8192 + rn * 64 + cc * 16);
            }
            for (int mi = 0; mi < 4; ++mi)
                for (int nf = 0; nf < 4; ++nf)
                    acc[mi][nf] = __builtin_amdgcn_mfma_f32_16x16x32_bf16(
                        a[mi], b[nf], acc[mi][nf], 0, 0, 0);
        }
    }
    float t2v[4];
    for (int nf = 0; nf < 4; ++nf)
        t2v[nf] = s2t2[4096 + n0 + wn + nf * 16 + (lane & 15)];
    float g1 = 0.f, g5 = 0.f;
    for (int mi = 0; mi < 4; ++mi) {
        int rbase = m0 + wm + mi * 16 + (lane >> 4) * 4;
        float s2v[4];
        for (int j = 0; j < 4; ++j) s2v[j] = s2t2[rbase + j];
        for (int nf = 0; nf < 4; ++nf)
            for (int j = 0; j < 4; ++j) {
                float d2 = s2v[j] + t2v[nf] - 2.f * acc[mi][nf][j];
                d2 = fmaxf(d2, 0.f);
                g1 += __expf(-0.5f * d2);
                g5 += __expf(-0.02f * d2);
            }
    }
    for (int m = 1; m < 64; m <<= 1) { g1 += __shfl_xor(g1, m); g5 += __shfl_xor(g5, m); }
    // block-level reduce (reuse LDS), one plain store per block
    __syncthreads();
    float* red = (float*)lds;
    if (lane == 0) { red[w * 2] = g1; red[w * 2 + 1] = g5; }
    __syncthreads();
    if (tid == 0) {
        int bid = blockIdx.y * 32 + blockIdx.x;
        gk_part[bid * 2]     = red[0] + red[2] + red[4] + red[6];
        gk_part[bid * 2 + 1] = red[1] + red[3] + red[5] + red[7];
    }
}

// ---------------- kernel 7: finalize scalars ----------------------------
__global__ void k_finalize(const float* __restrict__ colsum_part,
                           const float* __restrict__ gk_part,
                           const float* __restrict__ accs, float* __restrict__ d_out) {
    __shared__ float red[12];
    int tid = threadIdx.x, lane = tid & 63, w = tid >> 6;
    float cs = 0.f, ct = 0.f;
    for (int b = 0; b < 128; ++b)   cs += colsum_part[b * 256 + tid];
    for (int b = 128; b < 256; ++b) ct += colsum_part[b * 256 + tid];
    float delta = (cs - ct) * (1.f / 4096.f);
    float sq = delta * delta;
    float g1 = 0.f, g5 = 0.f;
    for (int i = 0; i < 4; ++i) {
        int p = tid * 4 + i;
        g1 += gk_part[p * 2];
        g5 += gk_part[p * 2 + 1];
    }
    for (int m = 1; m < 64; m <<= 1) {
        sq += __shfl_xor(sq, m);
        g1 += __shfl_xor(g1, m);
        g5 += __shfl_xor(g5, m);
    }
    if (lane == 0) { red[w * 3] = sq; red[w * 3 + 1] = g1; red[w * 3 + 2] = g5; }
    __syncthreads();
    if (tid == 0) {
        d_out[0] = accs[0] * (1.f / 4096.f);
        d_out[1] = red[0] + red[3] + red[6] + red[9];
        d_out[2] = (red[1] + red[4] + red[7] + red[10]) * 5.9604644775390625e-08f;
        d_out[3] = (red[2] + red[5] + red[8] + red[11]) * 5.9604644775390625e-08f;
    }
}

extern "C" void kernel_launch(void* const* d_in, const int* in_sizes, int n_in,
                              void* d_out, int out_size, void* d_ws, size_t ws_size,
                              hipStream_t stream) {
    const float* source = (const float*)d_in[0];
    const float* target = (const float*)d_in[1];
    const float* Wb     = (const float*)d_in[2];
    const float* bb     = (const float*)d_in[3];
    const float* Wc     = (const float*)d_in[4];
    const float* bc     = (const float*)d_in[5];
    const int*   labels = (const int*)d_in[6];
    float* out = (float*)d_out;
    uint8_t* ws = (uint8_t*)d_ws;

    uint16_t* Y    = (uint16_t*)(ws);                 // 8192*256*2 = 4 MB
    uint16_t* WbT  = (uint16_t*)(ws + 4194304);       // 1 MB (dead after k_bottleneck)
    uint16_t* WcT  = (uint16_t*)(ws + 5242880);       // 16 KB
    float*    s2t2 = (float*)(ws + 5259264);          // 32 KB
    float*    accs = (float*)(ws + 5292032);          // [ce, pad...]
    // alias the dead WbT region (only read by k_bottleneck, which runs first):
    float*    colsum_part = (float*)(ws + 4194304);             // 256*256 fl = 256 KB
    float*    gk_part     = (float*)(ws + 4194304 + 262144);    // 1024*2 fl = 8 KB

    k_init<<<1, 256, 0, stream>>>(Wc, WcT, accs);
    k_transpose_wb<<<dim3(64, 8), 256, 0, stream>>>(Wb, WbT);
    k_bottleneck<<<512, 256, 0, stream>>>(source, target, WbT, bb, Y);
    k_stats<<<256, 256, 0, stream>>>(Y, s2t2, colsum_part);
    k_classifier<<<128, 256, 0, stream>>>(Y, WcT, bc, labels, out + 4, accs);
    k_pairwise<<<dim3(32, 32), 256, 0, stream>>>(Y, s2t2, gk_part);
    k_finalize<<<1, 256, 0, stream>>>(colsum_part, gk_part, accs, out);
}

// Round 7
// 167.028 us; speedup vs baseline: 1.1428x; 1.0519x over previous
//
#include <hip/hip_runtime.h>
#include <stdint.h>

#define DI __device__ __forceinline__

typedef float f32x4 __attribute__((ext_vector_type(4)));
typedef short bf16x8 __attribute__((ext_vector_type(8)));

DI uint16_t f2bf(float f) {
    union { float f; uint32_t u; } v; v.f = f;
    uint32_t r = v.u + 0x7FFF + ((v.u >> 16) & 1);
    return (uint16_t)(r >> 16);
}
DI float bf2f(uint16_t h) {
    union { uint32_t u; float f; } v; v.u = ((uint32_t)h) << 16;
    return v.f;
}
// async global->LDS, 16B per lane; LDS dest = wave-uniform base + lane*16
DI void gl_lds16(const void* g, void* l) {
    __builtin_amdgcn_global_load_lds(
        (__attribute__((address_space(1))) void*)(uintptr_t)g,
        (__attribute__((address_space(3))) void*)(uintptr_t)l,
        16, 0, 0);
}

// ---------------- kernel 0: zero ce acc + Wc^T bf16 (pad 31->32) ----------
__global__ void k_init(const float* __restrict__ Wc, uint16_t* __restrict__ WcT,
                       float* __restrict__ accs) {
    int tid = threadIdx.x;
    if (tid < 4) accs[tid] = 0.f;
    for (int idx = tid; idx < 32 * 256; idx += 256) {
        int n = idx >> 8, k = idx & 255;
        WcT[idx] = (n < 31) ? f2bf(Wc[k * 31 + n]) : (uint16_t)0;
    }
}

// ---------------- kernel 1: Wb [2048][256] -> WbT bf16 [256][2048] --------
__global__ void k_transpose_wb(const float* __restrict__ Wb, uint16_t* __restrict__ WbT) {
    __shared__ float t[32][33];
    int kb = blockIdx.x, nb = blockIdx.y;
    int tx = threadIdx.x & 31, ty0 = (threadIdx.x >> 5) * 4;
    for (int i = 0; i < 4; ++i)
        t[ty0 + i][tx] = Wb[(kb * 32 + ty0 + i) * 256 + nb * 32 + tx];
    __syncthreads();
    for (int i = 0; i < 4; ++i)
        WbT[(nb * 32 + ty0 + i) * 2048 + kb * 32 + tx] = f2bf(t[tx][ty0 + i]);
}

// ---------------- kernel 2: Y = relu([src;tar] @ Wb + bb), bf16 out -------
// tile 32(m) x 128(n), BK=128 -> 16 iterations (was 32): halves the
// per-iteration fixed overhead (barrier+waits) which R2/R3/R6 showed is the
// dominant cost. 2-buffer A+B LDS, A 2-deep reg prefetch, counted vmcnt.
// grid 512 -> 2 blocks/CU. LDS 80KB/block.
__launch_bounds__(256)
__global__ void k_bottleneck(const float* __restrict__ src, const float* __restrict__ tgt,
                             const uint16_t* __restrict__ WbT, const float* __restrict__ bb,
                             uint16_t* __restrict__ Y) {
    // LA[2]: 8KB @0, @8192 ; LB[2]: 32KB @16384, @49152
    __shared__ __align__(16) uint8_t lds[81920];
    int tid = threadIdx.x;
    int lane = tid & 63, w = tid >> 6;
    int bm = blockIdx.x >> 1, bn = blockIdx.x & 1;   // N-halves of same A adjacent
    int m0 = bm * 32;
    const float* X = (m0 < 4096) ? (src + (size_t)m0 * 2048)
                                 : (tgt + (size_t)(m0 - 4096) * 2048);
    // A-staging: 16 fp32 per thread (two 8-fp32 chunks, k-blocks akb and akb+2)
    int ar = tid >> 3, akb = (tid >> 2) & 1, ap = tid & 3;
    int ac = ap ^ (ar & 3) ^ ((ar >> 2) & 3);
    const float* Ag = X + ar * 2048 + akb * 32 + ac * 8;
    const int AwOff = akb * 2048 + ar * 64 + ap * 16;
    int cc = (lane >> 4) ^ (lane & 3) ^ ((lane >> 2) & 3);
    // B-stage: 8 segs/wave of 1KB; seg i covers kb-block w, rows i*16..+16
    const uint16_t* Bg0; const uint16_t* Bg1; const uint16_t* Bg2; const uint16_t* Bg3;
    const uint16_t* Bg4; const uint16_t* Bg5; const uint16_t* Bg6; const uint16_t* Bg7;
    {
        int p = lane & 3;
        #define BGADDR(ii) ({ int r_ = (ii) * 16 + (lane >> 2); \
            int c_ = p ^ (r_ & 3) ^ ((r_ >> 2) & 3); \
            WbT + (size_t)(bn * 128 + r_) * 2048 + w * 32 + c_ * 8; })
        Bg0 = BGADDR(0); Bg1 = BGADDR(1); Bg2 = BGADDR(2); Bg3 = BGADDR(3);
        Bg4 = BGADDR(4); Bg5 = BGADDR(5); Bg6 = BGADDR(6); Bg7 = BGADDR(7);
        #undef BGADDR
    }
    const int lbB = 16384 + w * 8192;   // wave w's 8 segs (kb-block w) in LB buffer

    f32x4 acc[2][2] = {};
    float4 rE0, rE1, rE2, rE3, rO0, rO1, rO2, rO3;

    #define STAGE_B(buf, k0) do { \
        gl_lds16(Bg0 + (k0), lds + lbB + (buf) * 32768 + 0);    \
        gl_lds16(Bg1 + (k0), lds + lbB + (buf) * 32768 + 1024); \
        gl_lds16(Bg2 + (k0), lds + lbB + (buf) * 32768 + 2048); \
        gl_lds16(Bg3 + (k0), lds + lbB + (buf) * 32768 + 3072); \
        gl_lds16(Bg4 + (k0), lds + lbB + (buf) * 32768 + 4096); \
        gl_lds16(Bg5 + (k0), lds + lbB + (buf) * 32768 + 5120); \
        gl_lds16(Bg6 + (k0), lds + lbB + (buf) * 32768 + 6144); \
        gl_lds16(Bg7 + (k0), lds + lbB + (buf) * 32768 + 7168); \
    } while (0)

    #define LOAD_A(R0, R1, R2, R3, t) do { \
        R0 = *(const float4*)(Ag + (t) * 128);      \
        R1 = *(const float4*)(Ag + (t) * 128 + 4);  \
        R2 = *(const float4*)(Ag + (t) * 128 + 64); \
        R3 = *(const float4*)(Ag + (t) * 128 + 68); \
    } while (0)

    #define WRITE_A(par, a0, a1, a2, a3) do { \
        uint4 u_, v_; \
        u_.x = (uint32_t)f2bf((a0).x) | ((uint32_t)f2bf((a0).y) << 16); \
        u_.y = (uint32_t)f2bf((a0).z) | ((uint32_t)f2bf((a0).w) << 16); \
        u_.z = (uint32_t)f2bf((a1).x) | ((uint32_t)f2bf((a1).y) << 16); \
        u_.w = (uint32_t)f2bf((a1).z) | ((uint32_t)f2bf((a1).w) << 16); \
        v_.x = (uint32_t)f2bf((a2).x) | ((uint32_t)f2bf((a2).y) << 16); \
        v_.y = (uint32_t)f2bf((a2).z) | ((uint32_t)f2bf((a2).w) << 16); \
        v_.z = (uint32_t)f2bf((a3).x) | ((uint32_t)f2bf((a3).y) << 16); \
        v_.w = (uint32_t)f2bf((a3).z) | ((uint32_t)f2bf((a3).w) << 16); \
        *(uint4*)(lds + (par) * 8192 + AwOff) = u_; \
        *(uint4*)(lds + (par) * 8192 + AwOff + 4096) = v_; \
    } while (0)

    #define COMPUTE(par) do { \
        _Pragma("unroll") \
        for (int kb = 0; kb < 4; ++kb) { \
            bf16x8 a_[2], b_[2]; \
            _Pragma("unroll") \
            for (int mi = 0; mi < 2; ++mi) \
                a_[mi] = *(const bf16x8*)(lds + (par) * 8192 + kb * 2048 + \
                                          (mi * 16 + (lane & 15)) * 64 + cc * 16); \
            _Pragma("unroll") \
            for (int nf = 0; nf < 2; ++nf) \
                b_[nf] = *(const bf16x8*)(lds + 16384 + (par) * 32768 + kb * 8192 + \
                                          (w * 32 + nf * 16 + (lane & 15)) * 64 + cc * 16); \
            _Pragma("unroll") \
            for (int mi = 0; mi < 2; ++mi) \
                _Pragma("unroll") \
                for (int nf = 0; nf < 2; ++nf) \
                    acc[mi][nf] = __builtin_amdgcn_mfma_f32_16x16x32_bf16( \
                        a_[mi], b_[nf], acc[mi][nf], 0, 0, 0); \
        } \
    } while (0)

    #define FENCE() asm volatile("" ::: "memory")

    // ---- prologue: queue = [B0(8), A0(4), A1(4)] ----
    STAGE_B(0, 0);
    FENCE();
    LOAD_A(rE0, rE1, rE2, rE3, 0);                   // A(0)
    FENCE();
    LOAD_A(rO0, rO1, rO2, rO3, 1);                   // A(1)
    asm volatile("s_waitcnt vmcnt(4)" ::: "memory"); // drains B0+A0; A1 in flight
    WRITE_A(0, rE0, rE1, rE2, rE3);
    asm volatile("s_waitcnt lgkmcnt(0)" ::: "memory");
    __builtin_amdgcn_s_barrier();

    // ---- main loop t = 0..13 (2x unrolled by parity) ----
    // invariant at iter t entry: outstanding vmem = A(t+1) regs (4 loads)
    #define ITER(tc, RL0, RL1, RL2, RL3, RW0, RW1, RW2, RW3, WPAR) do { \
        STAGE_B(((tc) + 1) & 1, ((tc) + 1) * 128);   /* B(t+1) [+8] */ \
        FENCE(); \
        LOAD_A(RL0, RL1, RL2, RL3, (tc) + 2);        /* A(t+2) [+4] */ \
        FENCE(); \
        COMPUTE((tc) & 1); \
        asm volatile("s_waitcnt vmcnt(12)" ::: "memory"); /* A(t+1) done */ \
        WRITE_A(((tc) + 1) & 1, RW0, RW1, RW2, RW3); \
        asm volatile("s_waitcnt vmcnt(4) lgkmcnt(0)" ::: "memory"); /* B(t+1) done */ \
        __builtin_amdgcn_s_barrier(); \
    } while (0)

    for (int t2 = 0; t2 < 7; ++t2) {
        int tb = t2 * 2;
        ITER(tb + 0, rE0, rE1, rE2, rE3, rO0, rO1, rO2, rO3, 1);
        ITER(tb + 1, rO0, rO1, rO2, rO3, rE0, rE1, rE2, rE3, 0);
    }
    // ---- t = 14: outstanding entry = [A15(4)]; stage B15, no A(16) ----
    STAGE_B(1, 15 * 128);
    FENCE();
    COMPUTE(0);
    asm volatile("s_waitcnt vmcnt(8)" ::: "memory");  // A(15) done
    WRITE_A(1, rO0, rO1, rO2, rO3);
    asm volatile("s_waitcnt vmcnt(0) lgkmcnt(0)" ::: "memory");
    __builtin_amdgcn_s_barrier();
    // ---- t = 15 ----
    COMPUTE(1);

    #undef ITER
    #undef STAGE_B
    #undef LOAD_A
    #undef WRITE_A
    #undef COMPUTE
    #undef FENCE

    for (int mi = 0; mi < 2; ++mi)
        for (int nf = 0; nf < 2; ++nf) {
            int col = bn * 128 + w * 32 + nf * 16 + (lane & 15);
            float bias = bb[col];
            for (int j = 0; j < 4; ++j) {
                int row = m0 + mi * 16 + (lane >> 4) * 4 + j;
                float v = acc[mi][nf][j] + bias;
                v = fmaxf(v, 0.f);
                Y[(size_t)row * 256 + col] = f2bf(v);
            }
        }
}

// ---------------- kernel 3: fused row sum-of-squares + column partials ----
// single pass over Y; grid 256 blocks x 32 rows; colsum_part is [256][256]
__launch_bounds__(256)
__global__ void k_stats(const uint16_t* __restrict__ Y, float* __restrict__ s2t2,
                        float* __restrict__ colsum_part) {
    __shared__ float cs[4][256];
    int tid = threadIdx.x, lane = tid & 63, w = tid >> 6;
    int r0 = blockIdx.x * 32 + w * 8;
    float c0 = 0.f, c1 = 0.f, c2 = 0.f, c3 = 0.f;
    for (int i = 0; i < 8; ++i) {
        int row = r0 + i;
        ushort4 v = *(const ushort4*)(Y + (size_t)row * 256 + lane * 4);
        float a = bf2f(v.x), b = bf2f(v.y), c = bf2f(v.z), d = bf2f(v.w);
        c0 += a; c1 += b; c2 += c; c3 += d;
        float s = a * a + b * b + c * c + d * d;
        for (int m = 1; m < 64; m <<= 1) s += __shfl_xor(s, m);
        if (lane == 0) s2t2[row] = s;
    }
    cs[w][lane * 4 + 0] = c0;
    cs[w][lane * 4 + 1] = c1;
    cs[w][lane * 4 + 2] = c2;
    cs[w][lane * 4 + 3] = c3;
    __syncthreads();
    colsum_part[blockIdx.x * 256 + tid] =
        cs[0][tid] + cs[1][tid] + cs[2][tid] + cs[3][tid];
}

// ---------------- kernel 5: classifier + softmax margins + CE -----------
__launch_bounds__(256)
__global__ void k_classifier(const uint16_t* __restrict__ Y, const uint16_t* __restrict__ WcT,
                             const float* __restrict__ bc, const int* __restrict__ labels,
                             float* __restrict__ out_margin, float* __restrict__ ce_acc) {
    __shared__ __align__(16) uint8_t lds[49152];  // A 32KB @0, B 16KB @32768
    int tid = threadIdx.x, lane = tid & 63, w = tid >> 6;
    int m0 = blockIdx.x * 64;
    int cc = (lane >> 4) ^ (lane & 3) ^ ((lane >> 2) & 3);
    for (int s = w; s < 48; s += 4) {
        int r, p, c;
        if (s < 32) {
            int kb = s >> 2, r0 = (s & 3) * 16;
            r = r0 + (lane >> 2); p = lane & 3;
            c = p ^ (r & 3) ^ ((r >> 2) & 3);
            gl_lds16(Y + (size_t)(m0 + r) * 256 + kb * 32 + c * 8, lds + s * 1024);
        } else {
            int s2 = s - 32;
            int kb = s2 >> 1, r0 = (s2 & 1) * 16;
            r = r0 + (lane >> 2); p = lane & 3;
            c = p ^ (r & 3) ^ ((r >> 2) & 3);
            gl_lds16(WcT + r * 256 + kb * 32 + c * 8, lds + 32768 + s2 * 1024);
        }
    }
    __syncthreads();
    f32x4 acc[2] = {};
    for (int kb = 0; kb < 8; ++kb) {
        int r = w * 16 + (lane & 15);
        bf16x8 a = *(const bf16x8*)(lds + kb * 4096 + r * 64 + cc * 16);
        for (int nf = 0; nf < 2; ++nf) {
            int rn = nf * 16 + (lane & 15);
            bf16x8 b = *(const bf16x8*)(lds + 32768 + kb * 2048 + rn * 64 + cc * 16);
            acc[nf] = __builtin_amdgcn_mfma_f32_16x16x32_bf16(a, b, acc[nf], 0, 0, 0);
        }
    }
    int c0 = lane & 15, c1 = 16 + c0;
    float bc0 = bc[c0];
    float bc1 = (c1 < 31) ? bc[c1] : 0.f;
    bool is_src = (m0 < 4096);
    float ce_local = 0.f;
    for (int j = 0; j < 4; ++j) {
        int row = m0 + w * 16 + (lane >> 4) * 4 + j;
        float v0 = acc[0][j] + bc0;
        float v1 = (c1 < 31) ? (acc[1][j] + bc1) : -1e30f;
        float mx = fmaxf(v0, v1);
        for (int m = 1; m < 16; m <<= 1) mx = fmaxf(mx, __shfl_xor(mx, m, 16));
        float e0 = __expf(v0 - mx);
        float e1 = (c1 < 31) ? __expf(v1 - mx) : 0.f;
        float ssum = e0 + e1;
        for (int m = 1; m < 16; m <<= 1) ssum += __shfl_xor(ssum, m, 16);
        float inv = 1.f / ssum;
        float conf0 = e0 * inv, conf1 = e1 * inv;
        int lab;
        if (is_src) {
            lab = labels[row];
        } else {
            float bv; int bi;
            if (v0 >= v1) { bv = v0; bi = c0; } else { bv = v1; bi = c1; }
            for (int m = 1; m < 16; m <<= 1) {
                float ov = __shfl_xor(bv, m, 16);
                int oi = __shfl_xor(bi, m, 16);
                if (ov > bv || (ov == bv && oi < bi)) { bv = ov; bi = oi; }
            }
            lab = bi;
        }
        float tc = (c0 == lab ? conf0 : 0.f) + (c1 == lab ? conf1 : 0.f);
        for (int m = 1; m < 16; m <<= 1) tc += __shfl_xor(tc, m, 16);
        float ex = fmaxf(c0 == lab ? -1.f : conf0,
                         (c1 == lab || c1 >= 31) ? -1.f : conf1);
        for (int m = 1; m < 16; m <<= 1) ex = fmaxf(ex, __shfl_xor(ex, m, 16));
        if (c0 == 0) out_margin[row] = tc - ex;
        if (is_src) {
            float vl = (c0 == lab) ? v0 : ((c1 == lab) ? v1 : -1e30f);
            for (int m = 1; m < 16; m <<= 1) vl = fmaxf(vl, __shfl_xor(vl, m, 16));
            if (c0 == 0) ce_local += -(vl - mx - __logf(ssum));
        }
    }
    if (is_src) {
        ce_local += __shfl_xor(ce_local, 16);
        ce_local += __shfl_xor(ce_local, 32);
        if (lane == 0) atomicAdd(ce_acc, ce_local);   // 64 atomics total: fine
    }
}

// ---------------- kernel 6: pairwise d2 -> exp partial sums (no atomics) -
// 128x128 tile, K=256 staged in 2 halves of 64KB LDS
__launch_bounds__(256)
__global__ void k_pairwise(const uint16_t* __restrict__ Y, const float* __restrict__ s2t2,
                           float* __restrict__ gk_part) {
    __shared__ __align__(16) uint8_t lds[65536];  // A 32KB @0, B 32KB @32768
    int tid = threadIdx.x, lane = tid & 63, w = tid >> 6;
    int m0 = blockIdx.x * 128, n0 = blockIdx.y * 128;
    int cc = (lane >> 4) ^ (lane & 3) ^ ((lane >> 2) & 3);
    int wm = (w & 1) * 64, wn = (w >> 1) * 64;
    f32x4 acc[4][4] = {};
    for (int h = 0; h < 2; ++h) {
        if (h) __syncthreads();
        int k0 = h * 128;
        for (int i = 0; i < 8; ++i) {
            int s = w * 8 + i;
            int kb = s >> 3, r0 = (s & 7) * 16;
            int r = r0 + (lane >> 2), p = lane & 3;
            int c = p ^ (r & 3) ^ ((r >> 2) & 3);
            gl_lds16(Y + (size_t)(m0 + r) * 256 + k0 + kb * 32 + c * 8, lds + s * 1024);
            gl_lds16(Y + (size_t)(4096 + n0 + r) * 256 + k0 + kb * 32 + c * 8,
                     lds + 32768 + s * 1024);
        }
        __syncthreads();
        for (int kb = 0; kb < 4; ++kb) {
            bf16x8 a[4], b[4];
            for (int mi = 0; mi < 4; ++mi) {
                int r = wm + mi * 16 + (lane & 15);
                a[mi] = *(const bf16x8*)(lds + kb * 8192 + r * 64 + cc * 16);
            }
            for (int nf = 0; nf < 4; ++nf) {
                int rn = wn + nf * 16 + (lane & 15);
                b[nf] = *(const bf16x8*)(lds + 32768 + kb * 8192 + rn * 64 + cc * 16);
            }
            for (int mi = 0; mi < 4; ++mi)
                for (int nf = 0; nf < 4; ++nf)
                    acc[mi][nf] = __builtin_amdgcn_mfma_f32_16x16x32_bf16(
                        a[mi], b[nf], acc[mi][nf], 0, 0, 0);
        }
    }
    float t2v[4];
    for (int nf = 0; nf < 4; ++nf)
        t2v[nf] = s2t2[4096 + n0 + wn + nf * 16 + (lane & 15)];
    float g1 = 0.f, g5 = 0.f;
    for (int mi = 0; mi < 4; ++mi) {
        int rbase = m0 + wm + mi * 16 + (lane >> 4) * 4;
        float s2v[4];
        for (int j = 0; j < 4; ++j) s2v[j] = s2t2[rbase + j];
        for (int nf = 0; nf < 4; ++nf)
            for (int j = 0; j < 4; ++j) {
                float d2 = s2v[j] + t2v[nf] - 2.f * acc[mi][nf][j];
                d2 = fmaxf(d2, 0.f);
                g1 += __expf(-0.5f * d2);
                g5 += __expf(-0.02f * d2);
            }
    }
    for (int m = 1; m < 64; m <<= 1) { g1 += __shfl_xor(g1, m); g5 += __shfl_xor(g5, m); }
    // block-level reduce (reuse LDS), one plain store per block
    __syncthreads();
    float* red = (float*)lds;
    if (lane == 0) { red[w * 2] = g1; red[w * 2 + 1] = g5; }
    __syncthreads();
    if (tid == 0) {
        int bid = blockIdx.y * 32 + blockIdx.x;
        gk_part[bid * 2]     = red[0] + red[2] + red[4] + red[6];
        gk_part[bid * 2 + 1] = red[1] + red[3] + red[5] + red[7];
    }
}

// ---------------- kernel 7: finalize scalars ----------------------------
__global__ void k_finalize(const float* __restrict__ colsum_part,
                           const float* __restrict__ gk_part,
                           const float* __restrict__ accs, float* __restrict__ d_out) {
    __shared__ float red[12];
    int tid = threadIdx.x, lane = tid & 63, w = tid >> 6;
    float cs = 0.f, ct = 0.f;
    for (int b = 0; b < 128; ++b)   cs += colsum_part[b * 256 + tid];
    for (int b = 128; b < 256; ++b) ct += colsum_part[b * 256 + tid];
    float delta = (cs - ct) * (1.f / 4096.f);
    float sq = delta * delta;
    float g1 = 0.f, g5 = 0.f;
    for (int i = 0; i < 4; ++i) {
        int p = tid * 4 + i;
        g1 += gk_part[p * 2];
        g5 += gk_part[p * 2 + 1];
    }
    for (int m = 1; m < 64; m <<= 1) {
        sq += __shfl_xor(sq, m);
        g1 += __shfl_xor(g1, m);
        g5 += __shfl_xor(g5, m);
    }
    if (lane == 0) { red[w * 3] = sq; red[w * 3 + 1] = g1; red[w * 3 + 2] = g5; }
    __syncthreads();
    if (tid == 0) {
        d_out[0] = accs[0] * (1.f / 4096.f);
        d_out[1] = red[0] + red[3] + red[6] + red[9];
        d_out[2] = (red[1] + red[4] + red[7] + red[10]) * 5.9604644775390625e-08f;
        d_out[3] = (red[2] + red[5] + red[8] + red[11]) * 5.9604644775390625e-08f;
    }
}

extern "C" void kernel_launch(void* const* d_in, const int* in_sizes, int n_in,
                              void* d_out, int out_size, void* d_ws, size_t ws_size,
                              hipStream_t stream) {
    const float* source = (const float*)d_in[0];
    const float* target = (const float*)d_in[1];
    const float* Wb     = (const float*)d_in[2];
    const float* bb     = (const float*)d_in[3];
    const float* Wc     = (const float*)d_in[4];
    const float* bc     = (const float*)d_in[5];
    const int*   labels = (const int*)d_in[6];
    float* out = (float*)d_out;
    uint8_t* ws = (uint8_t*)d_ws;

    uint16_t* Y    = (uint16_t*)(ws);                 // 8192*256*2 = 4 MB
    uint16_t* WbT  = (uint16_t*)(ws + 4194304);       // 1 MB (dead after k_bottleneck)
    uint16_t* WcT  = (uint16_t*)(ws + 5242880);       // 16 KB
    float*    s2t2 = (float*)(ws + 5259264);          // 32 KB
    float*    accs = (float*)(ws + 5292032);          // [ce, pad...]
    // alias the dead WbT region (only read by k_bottleneck, which runs first):
    float*    colsum_part = (float*)(ws + 4194304);             // 256*256 fl = 256 KB
    float*    gk_part     = (float*)(ws + 4194304 + 262144);    // 1024*2 fl = 8 KB

    k_init<<<1, 256, 0, stream>>>(Wc, WcT, accs);
    k_transpose_wb<<<dim3(64, 8), 256, 0, stream>>>(Wb, WbT);
    k_bottleneck<<<512, 256, 0, stream>>>(source, target, WbT, bb, Y);
    k_stats<<<256, 256, 0, stream>>>(Y, s2t2, colsum_part);
    k_classifier<<<128, 256, 0, stream>>>(Y, WcT, bc, labels, out + 4, accs);
    k_pairwise<<<dim3(32, 32), 256, 0, stream>>>(Y, s2t2, gk_part);
    k_finalize<<<1, 256, 0, stream>>>(colsum_part, gk_part, accs, out);
}